// Round 2
// baseline (3350.532 us; speedup 1.0000x reference)
//
#include <hip/hip_runtime.h>

#define B_   128
#define DIM_ 768
#define NH_  12
#define HD_  64
#define N_   256

// ---------------------------------------------------------------------------
// Kernel 0: combined bias = face_prior[h,n,m] + rel_table[relidx(n,m), h]
// bias layout [NH, N, N]
// ---------------------------------------------------------------------------
__global__ __launch_bounds__(256) void bias_kernel(
    const float* __restrict__ face_prior,   // [1, NH, N, N]
    const float* __restrict__ rel_table,    // [961, NH]
    float* __restrict__ bias)               // [NH, N, N]
{
    int idx = blockIdx.x * 256 + threadIdx.x;     // over NH*N*N = 786432
    int m = idx & 255;
    int n = (idx >> 8) & 255;
    int h = idx >> 16;
    int rn = n >> 4, cn = n & 15;
    int rm = m >> 4, cm = m & 15;
    int ridx = (rn - rm + 15) * 31 + (cn - cm + 15);
    bias[idx] = face_prior[idx] + rel_table[ridx * NH_ + h];
}

// ---------------------------------------------------------------------------
// Kernel 1: QKV GEMM for a batch chunk [b0, b0+cb).
// A[m,k] = x[b*DIM*N + k*N + n]; out = A @ qkv_w^T + qkv_b,
// stored as q/k/v each [cb, NH, N, HD] (local batch index).
// tile 128(n) x 128(oc), BK=32, 256 threads, 8x8 acc per thread
// grid: (cb*2, 18)
// ---------------------------------------------------------------------------
__global__ __launch_bounds__(256) void qkv_gemm(
    const float* __restrict__ x, const float* __restrict__ w,
    const float* __restrict__ wb, float* __restrict__ qkv,
    int b0, int cb)
{
    const int tile_n  = blockIdx.x;
    const int tile_oc = blockIdx.y;
    const int bl = tile_n >> 1;            // local batch
    const int b  = b0 + bl;                // global batch
    const int n0 = (tile_n & 1) * 128;
    const int oc0 = tile_oc * 128;

    __shared__ float As[32][128];
    __shared__ float Bs[32][128];

    const int tid = threadIdx.x;
    const int tx = tid & 15;      // oc direction (coalesced qkv store)
    const int ty = tid >> 4;      // n direction

    float acc[8][8] = {};
    const float* xbase = x + (size_t)b * DIM_ * N_;

    for (int k0 = 0; k0 < DIM_; k0 += 32) {
        // A tile: As[kk][i] = x[(k0+kk)*N + n0+i]  (contiguous along i)
        #pragma unroll
        for (int s = 0; s < 4; ++s) {
            int flat = (tid + s * 256) * 4;
            int kk = flat >> 7;
            int i  = flat & 127;
            float4 av = *(const float4*)(xbase + (size_t)(k0 + kk) * N_ + n0 + i);
            *(float4*)&As[kk][i] = av;
        }
        // B tile: Bs[kk][j] = w[(oc0+j)*DIM + k0+kk]  (contiguous along k)
        #pragma unroll
        for (int s = 0; s < 4; ++s) {
            int flat = (tid + s * 256) * 4;
            int j  = flat >> 5;
            int kk = flat & 31;
            float4 wv = *(const float4*)(w + (size_t)(oc0 + j) * DIM_ + k0 + kk);
            Bs[kk + 0][j] = wv.x;
            Bs[kk + 1][j] = wv.y;
            Bs[kk + 2][j] = wv.z;
            Bs[kk + 3][j] = wv.w;
        }
        __syncthreads();
        #pragma unroll
        for (int kk = 0; kk < 32; ++kk) {
            float a[8], bb[8];
            *(float4*)&a[0]  = *(float4*)&As[kk][ty * 8];
            *(float4*)&a[4]  = *(float4*)&As[kk][ty * 8 + 4];
            *(float4*)&bb[0] = *(float4*)&Bs[kk][tx * 8];
            *(float4*)&bb[4] = *(float4*)&Bs[kk][tx * 8 + 4];
            #pragma unroll
            for (int ii = 0; ii < 8; ++ii)
                #pragma unroll
                for (int jj = 0; jj < 8; ++jj)
                    acc[ii][jj] += a[ii] * bb[jj];
        }
        __syncthreads();
    }

    // epilogue: +bias, scatter to q/k/v [which][cb,NH,N,HD]
    float bv[8];
    *(float4*)&bv[0] = *(const float4*)(wb + oc0 + tx * 8);
    *(float4*)&bv[4] = *(const float4*)(wb + oc0 + tx * 8 + 4);
    const size_t SLICE = (size_t)cb * NH_ * N_ * HD_;
    #pragma unroll
    for (int ii = 0; ii < 8; ++ii) {
        int n = n0 + ty * 8 + ii;
        #pragma unroll
        for (int jj = 0; jj < 8; jj += 4) {
            int oc = oc0 + tx * 8 + jj;
            int which = oc / DIM_;
            int r = oc - which * DIM_;
            int h = r >> 6;
            int d = r & 63;
            float4 v;
            v.x = acc[ii][jj + 0] + bv[jj + 0];
            v.y = acc[ii][jj + 1] + bv[jj + 1];
            v.z = acc[ii][jj + 2] + bv[jj + 2];
            v.w = acc[ii][jj + 3] + bv[jj + 3];
            *(float4*)(qkv + which * SLICE + (((size_t)bl * NH_ + h) * N_ + n) * HD_ + d) = v;
        }
    }
}

// ---------------------------------------------------------------------------
// Kernel 2: fused attention for a batch chunk. One block per (bl, h).
// 256 threads = 1 q-row each. K/V staged in LDS 64-row chunks; online softmax.
// grid: cb*NH
// ---------------------------------------------------------------------------
__global__ __launch_bounds__(256) void attn_kernel(
    const float* __restrict__ qkv,    // [3][cb,NH,N,HD]
    const float* __restrict__ bias,   // [NH,N,N]
    const float* __restrict__ fpri,   // face_priors [B,N,N]
    float* __restrict__ out,          // [cb,N,DIM]
    int b0, int cb)
{
    const int bh = blockIdx.x;
    const int bl = bh / NH_, h = bh % NH_;
    const int b = b0 + bl;
    const int n = threadIdx.x;

    __shared__ float Ks[64][64];
    __shared__ float Vs[64][64];

    const size_t SLICE = (size_t)cb * NH_ * N_ * HD_;
    const float* qp    = qkv + (((size_t)bl * NH_ + h) * N_ + n) * HD_;
    const float* kbase = qkv + SLICE     + (((size_t)bl * NH_ + h) * N_) * HD_;
    const float* vbase = qkv + 2 * SLICE + (((size_t)bl * NH_ + h) * N_) * HD_;
    const float* biasrow = bias + ((size_t)h * N_ + n) * N_;
    const float* fprow   = fpri + ((size_t)b * N_ + n) * N_;

    float q[64];
    #pragma unroll
    for (int d = 0; d < 64; d += 4) *(float4*)&q[d] = *(const float4*)(qp + d);

    float O[64] = {};
    float runmax = -1e30f, l = 0.f;
    const float scale = 0.125f;

    for (int c = 0; c < 4; ++c) {
        __syncthreads();
        int m0 = c * 64;
        #pragma unroll
        for (int s = 0; s < 4; ++s) {
            int flat = (threadIdx.x + s * 256) * 4;
            int row = flat >> 6, col = flat & 63;
            *(float4*)&Ks[row][col] = *(const float4*)(kbase + (size_t)(m0 + row) * HD_ + col);
            *(float4*)&Vs[row][col] = *(const float4*)(vbase + (size_t)(m0 + row) * HD_ + col);
        }
        __syncthreads();
        #pragma unroll
        for (int sub = 0; sub < 4; ++sub) {
            float s_[16];
            #pragma unroll
            for (int t4 = 0; t4 < 16; t4 += 4) {
                float4 bv = *(const float4*)(biasrow + m0 + sub * 16 + t4);
                float4 fv = *(const float4*)(fprow   + m0 + sub * 16 + t4);
                #pragma unroll
                for (int u = 0; u < 4; ++u) {
                    int mr = sub * 16 + t4 + u;
                    float acc = 0.f;
                    #pragma unroll
                    for (int d = 0; d < 64; ++d) acc += q[d] * Ks[mr][d];
                    float bb = (u == 0) ? bv.x : (u == 1) ? bv.y : (u == 2) ? bv.z : bv.w;
                    float ff = (u == 0) ? fv.x : (u == 1) ? fv.y : (u == 2) ? fv.z : fv.w;
                    s_[t4 + u] = (acc * scale + bb) * ff;
                }
            }
            float cmax = runmax;
            #pragma unroll
            for (int t = 0; t < 16; ++t) cmax = fmaxf(cmax, s_[t]);
            float corr = __expf(runmax - cmax);
            runmax = cmax;
            l *= corr;
            #pragma unroll
            for (int d = 0; d < 64; ++d) O[d] *= corr;
            #pragma unroll
            for (int t = 0; t < 16; ++t) {
                float p = __expf(s_[t] - cmax);
                l += p;
                int mr = sub * 16 + t;
                #pragma unroll
                for (int d = 0; d < 64; ++d) O[d] += p * Vs[mr][d];
            }
        }
    }
    float inv = 1.f / l;
    float* op = out + ((size_t)bl * N_ + n) * DIM_ + h * HD_;
    #pragma unroll
    for (int d = 0; d < 64; d += 4) {
        float4 v;
        v.x = O[d] * inv; v.y = O[d + 1] * inv;
        v.z = O[d + 2] * inv; v.w = O[d + 3] * inv;
        *(float4*)(op + d) = v;
    }
}

// ---------------------------------------------------------------------------
// Kernel 3: proj GEMM for a batch chunk. A[m,k] = attn_out[m*DIM + k],
// out[b*DIM*N + oc*N + n] = A @ proj_w^T + proj_b  (contig n on store)
// tile 128(n) x 128(oc), BK=32; grid: (cb*2, 6)
// ---------------------------------------------------------------------------
__global__ __launch_bounds__(256) void proj_gemm(
    const float* __restrict__ a, const float* __restrict__ w,
    const float* __restrict__ wb, float* __restrict__ out,
    int b0)
{
    const int tile_n  = blockIdx.x;
    const int tile_oc = blockIdx.y;
    const int bl = tile_n >> 1;
    const int b  = b0 + bl;
    const int n0 = (tile_n & 1) * 128;
    const int oc0 = tile_oc * 128;
    const int m0 = bl * N_ + n0;           // local row into a

    __shared__ float As[32][128];
    __shared__ float Bs[32][128];

    const int tid = threadIdx.x;
    const int tx = tid & 15;      // n direction
    const int ty = tid >> 4;      // oc direction

    float acc[8][8] = {};  // [ii over n][jj over oc]

    for (int k0 = 0; k0 < DIM_; k0 += 32) {
        // A tile: As[kk][i] = a[(m0+i)*DIM + k0+kk]
        #pragma unroll
        for (int s = 0; s < 4; ++s) {
            int flat = (tid + s * 256) * 4;
            int i  = flat >> 5;
            int kk = flat & 31;
            float4 av = *(const float4*)(a + (size_t)(m0 + i) * DIM_ + k0 + kk);
            As[kk + 0][i] = av.x;
            As[kk + 1][i] = av.y;
            As[kk + 2][i] = av.z;
            As[kk + 3][i] = av.w;
        }
        // B tile: Bs[kk][j] = w[(oc0+j)*DIM + k0+kk]
        #pragma unroll
        for (int s = 0; s < 4; ++s) {
            int flat = (tid + s * 256) * 4;
            int j  = flat >> 5;
            int kk = flat & 31;
            float4 wv = *(const float4*)(w + (size_t)(oc0 + j) * DIM_ + k0 + kk);
            Bs[kk + 0][j] = wv.x;
            Bs[kk + 1][j] = wv.y;
            Bs[kk + 2][j] = wv.z;
            Bs[kk + 3][j] = wv.w;
        }
        __syncthreads();
        #pragma unroll
        for (int kk = 0; kk < 32; ++kk) {
            float av[8], bb[8];
            *(float4*)&av[0] = *(float4*)&As[kk][tx * 8];
            *(float4*)&av[4] = *(float4*)&As[kk][tx * 8 + 4];
            *(float4*)&bb[0] = *(float4*)&Bs[kk][ty * 8];
            *(float4*)&bb[4] = *(float4*)&Bs[kk][ty * 8 + 4];
            #pragma unroll
            for (int ii = 0; ii < 8; ++ii)
                #pragma unroll
                for (int jj = 0; jj < 8; ++jj)
                    acc[ii][jj] += av[ii] * bb[jj];
        }
        __syncthreads();
    }

    float pb[8];
    *(float4*)&pb[0] = *(const float4*)(wb + oc0 + ty * 8);
    *(float4*)&pb[4] = *(const float4*)(wb + oc0 + ty * 8 + 4);
    #pragma unroll
    for (int jj = 0; jj < 8; ++jj) {
        int oc = oc0 + ty * 8 + jj;
        float* orow = out + (size_t)b * DIM_ * N_ + (size_t)oc * N_ + n0 + tx * 8;
        float4 v0, v1;
        v0.x = acc[0][jj] + pb[jj]; v0.y = acc[1][jj] + pb[jj];
        v0.z = acc[2][jj] + pb[jj]; v0.w = acc[3][jj] + pb[jj];
        v1.x = acc[4][jj] + pb[jj]; v1.y = acc[5][jj] + pb[jj];
        v1.z = acc[6][jj] + pb[jj]; v1.w = acc[7][jj] + pb[jj];
        *(float4*)(orow)     = v0;
        *(float4*)(orow + 4) = v1;
    }
}

// ---------------------------------------------------------------------------
extern "C" void kernel_launch(void* const* d_in, const int* in_sizes, int n_in,
                              void* d_out, int out_size, void* d_ws, size_t ws_size,
                              hipStream_t stream)
{
    const float* x           = (const float*)d_in[0];
    const float* face_priors = (const float*)d_in[1];
    const float* qkv_w       = (const float*)d_in[2];
    const float* qkv_b       = (const float*)d_in[3];
    const float* rel_table   = (const float*)d_in[4];
    const float* face_prior  = (const float*)d_in[5];
    const float* proj_w      = (const float*)d_in[6];
    const float* proj_b      = (const float*)d_in[7];
    float* out = (float*)d_out;

    // Workspace budget: bias (786432 floats) + per-chunk qkv (CB*589824) +
    // per-chunk attn_out (CB*196608)  =>  (CB+1) * 3145728 bytes.
    // Pick the largest chunk CB that fits ws_size (deterministic per call).
    int CB = 1;
    const int cands[] = {128, 64, 32, 16, 8, 4, 2, 1};
    for (int ci = 0; ci < 8; ++ci) {
        if ((size_t)(cands[ci] + 1) * 3145728u <= ws_size) { CB = cands[ci]; break; }
    }

    float* ws = (float*)d_ws;
    float* bias  = ws;                                   // 786432 floats
    float* qkvb  = bias + 786432;                        // 3*CB*NH*N*HD floats
    float* attnb = qkvb + (size_t)3 * CB * NH_ * N_ * HD_; // CB*N*DIM floats

    bias_kernel<<<(NH_ * N_ * N_) / 256, 256, 0, stream>>>(face_prior, rel_table, bias);

    for (int b0 = 0; b0 < B_; b0 += CB) {
        dim3 g1(CB * 2, 18);
        qkv_gemm<<<g1, 256, 0, stream>>>(x, qkv_w, qkv_b, qkvb, b0, CB);

        attn_kernel<<<CB * NH_, 256, 0, stream>>>(qkvb, bias, face_priors, attnb, b0, CB);

        dim3 g3(CB * 2, 6);
        proj_gemm<<<g3, 256, 0, stream>>>(attnb, proj_w, proj_b, out, b0);
    }
}

// Round 3
// 2125.548 us; speedup vs baseline: 1.5763x; 1.5763x over previous
//
#include <hip/hip_runtime.h>

#define B_   128
#define DIM_ 768
#define NH_  12
#define HD_  64
#define N_   256

using short8 = __attribute__((ext_vector_type(8))) short;
using f32x4  = __attribute__((ext_vector_type(4))) float;
typedef unsigned short u16;
typedef unsigned int   u32;

__device__ __forceinline__ u16 f2bf_hi(float f) {
    union { float f; u32 u; } v; v.f = f;
    u32 r = (v.u + 0x7fffu + ((v.u >> 16) & 1u)) >> 16;   // RNE
    return (u16)r;
}
__device__ __forceinline__ float bf2f(u16 h) {
    union { u32 u; float f; } v; v.u = ((u32)h) << 16;
    return v.f;
}

// ---------------------------------------------------------------------------
// bias = face_prior[h,n,m] + rel_table[relidx(n,m), h]   -> [NH, N, N]
// ---------------------------------------------------------------------------
__global__ __launch_bounds__(256) void bias_kernel(
    const float* __restrict__ face_prior, const float* __restrict__ rel_table,
    float* __restrict__ bias)
{
    int idx = blockIdx.x * 256 + threadIdx.x;
    int m = idx & 255;
    int n = (idx >> 8) & 255;
    int h = idx >> 16;
    int rn = n >> 4, cn = n & 15;
    int rm = m >> 4, cm = m & 15;
    int ridx = (rn - rm + 15) * 31 + (cn - cm + 15);
    bias[idx] = face_prior[idx] + rel_table[ridx * NH_ + h];
}

// ---------------------------------------------------------------------------
// split weights: fp32 [count] -> hi/lo bf16 (same layout). n8 = count/8.
// ---------------------------------------------------------------------------
__global__ __launch_bounds__(256) void split_w_kernel(
    const float* __restrict__ in, u16* __restrict__ hi, u16* __restrict__ lo, int n8)
{
    int i = blockIdx.x * 256 + threadIdx.x;
    if (i >= n8) return;
    float4 a = *(const float4*)(in + (size_t)i * 8);
    float4 b = *(const float4*)(in + (size_t)i * 8 + 4);
    float v[8] = {a.x, a.y, a.z, a.w, b.x, b.y, b.z, b.w};
    union { u16 s[8]; uint4 q; } H, L;
    #pragma unroll
    for (int j = 0; j < 8; ++j) {
        u16 h = f2bf_hi(v[j]);
        H.s[j] = h;
        L.s[j] = f2bf_hi(v[j] - bf2f(h));
    }
    *(uint4*)(hi + (size_t)i * 8) = H.q;
    *(uint4*)(lo + (size_t)i * 8) = L.q;
}

// ---------------------------------------------------------------------------
// split + transpose x: [B, 768(k), 256(n)] fp32 -> hi/lo bf16 [B, 256(n), 768(k)]
// grid (12 kt, 4 nt, B)
// ---------------------------------------------------------------------------
__global__ __launch_bounds__(256) void split_transpose_x(
    const float* __restrict__ x, u16* __restrict__ hi, u16* __restrict__ lo)
{
    __shared__ float T[64][65];
    const int b = blockIdx.z, k0 = blockIdx.x * 64, n0 = blockIdx.y * 64;
    const int t = threadIdx.x;
    const float* xb = x + (size_t)b * DIM_ * N_;
    {
        int nn = t & 63, kg = t >> 6;
        #pragma unroll
        for (int r = 0; r < 16; ++r) {
            int kk = r * 4 + kg;
            T[kk][nn] = xb[(size_t)(k0 + kk) * N_ + n0 + nn];
        }
    }
    __syncthreads();
    {
        int kk2 = (t & 31) * 2, ng = t >> 5;
        #pragma unroll
        for (int r = 0; r < 8; ++r) {
            int nn = r * 8 + ng;
            float v0 = T[kk2][nn], v1 = T[kk2 + 1][nn];
            u16 h0 = f2bf_hi(v0), h1 = f2bf_hi(v1);
            u16 l0 = f2bf_hi(v0 - bf2f(h0)), l1 = f2bf_hi(v1 - bf2f(h1));
            size_t o = ((size_t)b * N_ + n0 + nn) * DIM_ + k0 + kk2;
            *(u32*)(hi + o) = (u32)h0 | ((u32)h1 << 16);
            *(u32*)(lo + o) = (u32)l0 | ((u32)l1 << 16);
        }
    }
}

// ---------------------------------------------------------------------------
// Split-bf16 MFMA GEMM:  D[oc][n] = sum_k W[oc][k] * X[n][k]  (+bias)
// A-operand = W-tile (16oc x 32k), B-operand = X-tile (32k x 16n).
// 3-term: Ah*Bh + Ah*Bl + Al*Bh  (near-fp32 accuracy).
// tile 128(oc) x 128(n), BK=32, 4 waves in 2x2, 4x4 16x16 frags per wave.
// MODE 0: qkv epilogue (scatter to q/k/v [cb,NH,N,HD], d-contig float4)
// MODE 1: proj epilogue (out[b, oc, n], scalar stores, n-coalesced)
// grid (cb*2, 18|6)
// ---------------------------------------------------------------------------
template<int MODE>
__global__ __launch_bounds__(256) void gemm_split(
    const u16* __restrict__ wh, const u16* __restrict__ wl,
    const u16* __restrict__ xh, const u16* __restrict__ xl,
    const float* __restrict__ bvec, float* __restrict__ outp,
    int b0, int cb)
{
    __shared__ u16 Wh[128][40], Wl[128][40], Xh[128][40], Xl[128][40];

    const int tid  = threadIdx.x;
    const int lane = tid & 63;
    const int wv   = tid >> 6;
    const int wr   = wv >> 1;          // oc dir (0..1)
    const int wc   = wv & 1;           // n  dir (0..1)
    const int bx = blockIdx.x, by = blockIdx.y;
    const int bl = bx >> 1, half = bx & 1;
    const int b  = b0 + bl;

    const size_t wrow0 = (size_t)by * 128;
    const size_t xrow0 = (MODE == 0 ? (size_t)b * N_ : (size_t)bl * N_) + half * 128;

    const int srow = tid >> 2;         // staging: chunk row (0..63), +64 for s=1
    const int skc  = tid & 3;          // staging: 16B chunk within row

    f32x4 acc[4][4];
    #pragma unroll
    for (int i = 0; i < 4; ++i)
        #pragma unroll
        for (int j = 0; j < 4; ++j)
            acc[i][j] = (f32x4){0.f, 0.f, 0.f, 0.f};

    const int lrow = lane & 15;
    const int lkc  = (lane >> 4) * 8;  // ushort offset within row

    for (int k0 = 0; k0 < DIM_; k0 += 32) {
        #pragma unroll
        for (int s = 0; s < 2; ++s) {
            int row = srow + s * 64;
            int ko  = k0 + skc * 8;
            size_t wsrc = (wrow0 + row) * DIM_ + ko;
            size_t xsrc = (xrow0 + row) * DIM_ + ko;
            uint4 a0 = *(const uint4*)(wh + wsrc);
            uint4 a1 = *(const uint4*)(wl + wsrc);
            uint4 a2 = *(const uint4*)(xh + xsrc);
            uint4 a3 = *(const uint4*)(xl + xsrc);
            *(uint4*)&Wh[row][skc * 8] = a0;
            *(uint4*)&Wl[row][skc * 8] = a1;
            *(uint4*)&Xh[row][skc * 8] = a2;
            *(uint4*)&Xl[row][skc * 8] = a3;
        }
        __syncthreads();

        short8 ah[4], al[4];
        #pragma unroll
        for (int mt = 0; mt < 4; ++mt) {
            int r = wr * 64 + mt * 16 + lrow;
            ah[mt] = *(const short8*)&Wh[r][lkc];
            al[mt] = *(const short8*)&Wl[r][lkc];
        }
        #pragma unroll
        for (int nt = 0; nt < 4; ++nt) {
            int r = wc * 64 + nt * 16 + lrow;
            short8 bh = *(const short8*)&Xh[r][lkc];
            short8 bo = *(const short8*)&Xl[r][lkc];
            #pragma unroll
            for (int mt = 0; mt < 4; ++mt) {
                acc[mt][nt] = __builtin_amdgcn_mfma_f32_16x16x32_bf16(ah[mt], bh, acc[mt][nt], 0, 0, 0);
                acc[mt][nt] = __builtin_amdgcn_mfma_f32_16x16x32_bf16(ah[mt], bo, acc[mt][nt], 0, 0, 0);
                acc[mt][nt] = __builtin_amdgcn_mfma_f32_16x16x32_bf16(al[mt], bh, acc[mt][nt], 0, 0, 0);
            }
        }
        __syncthreads();
    }

    // C/D layout (m89-verified): col = lane&15, row = (lane>>4)*4 + reg
    const int ocb = by * 128 + wr * 64 + (lane >> 4) * 4;
    const int nb  = half * 128 + wc * 64 + (lane & 15);

    if (MODE == 0) {
        const size_t SLICE = (size_t)cb * NH_ * N_ * HD_;
        #pragma unroll
        for (int mt = 0; mt < 4; ++mt) {
            int oc = ocb + mt * 16;
            float4 bv = *(const float4*)(bvec + oc);
            int which = oc / DIM_;
            int r = oc - which * DIM_;
            int h = r >> 6, d = r & 63;
            float* obase = outp + which * SLICE + ((size_t)bl * NH_ + h) * N_ * HD_ + d;
            #pragma unroll
            for (int nt = 0; nt < 4; ++nt) {
                int n = nb + nt * 16;
                float4 o;
                o.x = acc[mt][nt][0] + bv.x;
                o.y = acc[mt][nt][1] + bv.y;
                o.z = acc[mt][nt][2] + bv.z;
                o.w = acc[mt][nt][3] + bv.w;
                *(float4*)(obase + (size_t)n * HD_) = o;
            }
        }
    } else {
        #pragma unroll
        for (int mt = 0; mt < 4; ++mt) {
            int oc = ocb + mt * 16;
            float4 bv = *(const float4*)(bvec + oc);
            float* obase = outp + (size_t)b * DIM_ * N_ + (size_t)oc * N_;
            #pragma unroll
            for (int nt = 0; nt < 4; ++nt) {
                int n = nb + nt * 16;
                obase[0 * N_ + n] = acc[mt][nt][0] + bv.x;
                obase[1 * N_ + n] = acc[mt][nt][1] + bv.y;
                obase[2 * N_ + n] = acc[mt][nt][2] + bv.z;
                obase[3 * N_ + n] = acc[mt][nt][3] + bv.w;
            }
        }
    }
}

// ---------------------------------------------------------------------------
// fused attention (unchanged math); epilogue emits hi/lo bf16 for proj GEMM
// ---------------------------------------------------------------------------
__global__ __launch_bounds__(256) void attn_kernel(
    const float* __restrict__ qkv,    // [3][cb,NH,N,HD]
    const float* __restrict__ bias,   // [NH,N,N]
    const float* __restrict__ fpri,   // [B,N,N]
    u16* __restrict__ aoh, u16* __restrict__ aol,   // [cb*N, DIM] bf16 splits
    int b0, int cb)
{
    const int bh = blockIdx.x;
    const int bl = bh / NH_, h = bh % NH_;
    const int b = b0 + bl;
    const int n = threadIdx.x;

    __shared__ float Ks[64][64];
    __shared__ float Vs[64][64];

    const size_t SLICE = (size_t)cb * NH_ * N_ * HD_;
    const float* qp    = qkv + (((size_t)bl * NH_ + h) * N_ + n) * HD_;
    const float* kbase = qkv + SLICE     + (((size_t)bl * NH_ + h) * N_) * HD_;
    const float* vbase = qkv + 2 * SLICE + (((size_t)bl * NH_ + h) * N_) * HD_;
    const float* biasrow = bias + ((size_t)h * N_ + n) * N_;
    const float* fprow   = fpri + ((size_t)b * N_ + n) * N_;

    float q[64];
    #pragma unroll
    for (int d = 0; d < 64; d += 4) *(float4*)&q[d] = *(const float4*)(qp + d);

    float O[64] = {};
    float runmax = -1e30f, l = 0.f;
    const float scale = 0.125f;

    for (int c = 0; c < 4; ++c) {
        __syncthreads();
        int m0 = c * 64;
        #pragma unroll
        for (int s = 0; s < 4; ++s) {
            int flat = (threadIdx.x + s * 256) * 4;
            int row = flat >> 6, col = flat & 63;
            *(float4*)&Ks[row][col] = *(const float4*)(kbase + (size_t)(m0 + row) * HD_ + col);
            *(float4*)&Vs[row][col] = *(const float4*)(vbase + (size_t)(m0 + row) * HD_ + col);
        }
        __syncthreads();
        #pragma unroll
        for (int sub = 0; sub < 4; ++sub) {
            float s_[16];
            #pragma unroll
            for (int t4 = 0; t4 < 16; t4 += 4) {
                float4 bv = *(const float4*)(biasrow + m0 + sub * 16 + t4);
                float4 fv = *(const float4*)(fprow   + m0 + sub * 16 + t4);
                #pragma unroll
                for (int u = 0; u < 4; ++u) {
                    int mr = sub * 16 + t4 + u;
                    float acc = 0.f;
                    #pragma unroll
                    for (int d = 0; d < 64; ++d) acc += q[d] * Ks[mr][d];
                    float bb = (u == 0) ? bv.x : (u == 1) ? bv.y : (u == 2) ? bv.z : bv.w;
                    float ff = (u == 0) ? fv.x : (u == 1) ? fv.y : (u == 2) ? fv.z : fv.w;
                    s_[t4 + u] = (acc * scale + bb) * ff;
                }
            }
            float cmax = runmax;
            #pragma unroll
            for (int t = 0; t < 16; ++t) cmax = fmaxf(cmax, s_[t]);
            float corr = __expf(runmax - cmax);
            runmax = cmax;
            l *= corr;
            #pragma unroll
            for (int d = 0; d < 64; ++d) O[d] *= corr;
            #pragma unroll
            for (int t = 0; t < 16; ++t) {
                float p = __expf(s_[t] - cmax);
                l += p;
                int mr = sub * 16 + t;
                #pragma unroll
                for (int d = 0; d < 64; ++d) O[d] += p * Vs[mr][d];
            }
        }
    }
    float inv = 1.f / l;
    size_t obase = ((size_t)bl * N_ + n) * DIM_ + h * HD_;
    #pragma unroll
    for (int d = 0; d < 64; d += 4) {
        union { u16 s[4]; uint2 q; } H, L;
        #pragma unroll
        for (int j = 0; j < 4; ++j) {
            float v = O[d + j] * inv;
            u16 hh = f2bf_hi(v);
            H.s[j] = hh;
            L.s[j] = f2bf_hi(v - bf2f(hh));
        }
        *(uint2*)(aoh + obase + d) = H.q;
        *(uint2*)(aol + obase + d) = L.q;
    }
}

// ---------------------------------------------------------------------------
extern "C" void kernel_launch(void* const* d_in, const int* in_sizes, int n_in,
                              void* d_out, int out_size, void* d_ws, size_t ws_size,
                              hipStream_t stream)
{
    const float* x           = (const float*)d_in[0];
    const float* face_priors = (const float*)d_in[1];
    const float* qkv_w       = (const float*)d_in[2];
    const float* qkv_b       = (const float*)d_in[3];
    const float* rel_table   = (const float*)d_in[4];
    const float* face_prior  = (const float*)d_in[5];
    const float* proj_w      = (const float*)d_in[6];
    const float* proj_b      = (const float*)d_in[7];
    float* out = (float*)d_out;

    // persistent: bias 3.15MB + xa splits 100.7MB + w splits 9.4MB = 113.25MB
    // per-chunk: qkv fp32 (CB*2.36MB) + ao splits (CB*0.79MB) = CB*3.146MB
    float* ws   = (float*)d_ws;
    float* bias = ws;                                       // 786432 f32
    u16* xah = (u16*)(bias + 786432);
    u16* xal = xah + (size_t)B_ * N_ * DIM_;
    u16* qwh = xal + (size_t)B_ * N_ * DIM_;
    u16* qwl = qwh + (size_t)3 * DIM_ * DIM_;
    u16* pwh = qwl + (size_t)3 * DIM_ * DIM_;
    u16* pwl = pwh + (size_t)DIM_ * DIM_;
    float* qkvb = (float*)(pwl + (size_t)DIM_ * DIM_);

    int CB = 1;
    const int cands[] = {128, 64, 32, 16, 8, 4, 2, 1};
    for (int ci = 0; ci < 8; ++ci) {
        if (113246208ull + (size_t)cands[ci] * 3145728ull <= ws_size) { CB = cands[ci]; break; }
    }
    u16* aoh = (u16*)(qkvb + (size_t)3 * CB * NH_ * N_ * HD_);
    u16* aol = aoh + (size_t)CB * N_ * DIM_;

    bias_kernel<<<(NH_ * N_ * N_) / 256, 256, 0, stream>>>(face_prior, rel_table, bias);
    split_w_kernel<<<(3 * DIM_ * DIM_ / 8 + 255) / 256, 256, 0, stream>>>(qkv_w, qwh, qwl, 3 * DIM_ * DIM_ / 8);
    split_w_kernel<<<(DIM_ * DIM_ / 8 + 255) / 256, 256, 0, stream>>>(proj_w, pwh, pwl, DIM_ * DIM_ / 8);
    split_transpose_x<<<dim3(12, 4, B_), 256, 0, stream>>>(x, xah, xal);

    for (int b0 = 0; b0 < B_; b0 += CB) {
        gemm_split<0><<<dim3(CB * 2, 18), 256, 0, stream>>>(qwh, qwl, xah, xal, qkv_b, qkvb, b0, CB);
        attn_kernel<<<CB * NH_, 256, 0, stream>>>(qkvb, bias, face_priors, aoh, aol, b0, CB);
        gemm_split<1><<<dim3(CB * 2, 6), 256, 0, stream>>>(pwh, pwl, aoh, aol, proj_b, out, b0, CB);
    }
}

// Round 4
// 1161.044 us; speedup vs baseline: 2.8858x; 1.8307x over previous
//
#include <hip/hip_runtime.h>

#define B_   128
#define DIM_ 768
#define NH_  12
#define HD_  64
#define N_   256

using short8 = __attribute__((ext_vector_type(8))) short;
using f32x4  = __attribute__((ext_vector_type(4))) float;
typedef unsigned short u16;
typedef unsigned int   u32;

__device__ __forceinline__ u16 f2bf_hi(float f) {
    union { float f; u32 u; } v; v.f = f;
    u32 r = (v.u + 0x7fffu + ((v.u >> 16) & 1u)) >> 16;   // RNE
    return (u16)r;
}
__device__ __forceinline__ float bf2f(u16 h) {
    union { u32 u; float f; } v; v.u = ((u32)h) << 16;
    return v.f;
}

// ---------------------------------------------------------------------------
// bias = face_prior[h,n,m] + rel_table[relidx(n,m), h]   -> [NH, N, N]
// ---------------------------------------------------------------------------
__global__ __launch_bounds__(256) void bias_kernel(
    const float* __restrict__ face_prior, const float* __restrict__ rel_table,
    float* __restrict__ bias)
{
    int idx = blockIdx.x * 256 + threadIdx.x;
    int m = idx & 255;
    int n = (idx >> 8) & 255;
    int h = idx >> 16;
    int rn = n >> 4, cn = n & 15;
    int rm = m >> 4, cm = m & 15;
    int ridx = (rn - rm + 15) * 31 + (cn - cm + 15);
    bias[idx] = face_prior[idx] + rel_table[ridx * NH_ + h];
}

// ---------------------------------------------------------------------------
// split weights: fp32 [count] -> hi/lo bf16 (same layout). n8 = count/8.
// ---------------------------------------------------------------------------
__global__ __launch_bounds__(256) void split_w_kernel(
    const float* __restrict__ in, u16* __restrict__ hi, u16* __restrict__ lo, int n8)
{
    int i = blockIdx.x * 256 + threadIdx.x;
    if (i >= n8) return;
    float4 a = *(const float4*)(in + (size_t)i * 8);
    float4 b = *(const float4*)(in + (size_t)i * 8 + 4);
    float v[8] = {a.x, a.y, a.z, a.w, b.x, b.y, b.z, b.w};
    union { u16 s[8]; uint4 q; } H, L;
    #pragma unroll
    for (int j = 0; j < 8; ++j) {
        u16 h = f2bf_hi(v[j]);
        H.s[j] = h;
        L.s[j] = f2bf_hi(v[j] - bf2f(h));
    }
    *(uint4*)(hi + (size_t)i * 8) = H.q;
    *(uint4*)(lo + (size_t)i * 8) = L.q;
}

// ---------------------------------------------------------------------------
// split + transpose x: [B, 768(k), 256(n)] fp32 -> hi/lo bf16 [B, 256(n), 768(k)]
// grid (12 kt, 4 nt, B)
// ---------------------------------------------------------------------------
__global__ __launch_bounds__(256) void split_transpose_x(
    const float* __restrict__ x, u16* __restrict__ hi, u16* __restrict__ lo)
{
    __shared__ float T[64][65];
    const int b = blockIdx.z, k0 = blockIdx.x * 64, n0 = blockIdx.y * 64;
    const int t = threadIdx.x;
    const float* xb = x + (size_t)b * DIM_ * N_;
    {
        int nn = t & 63, kg = t >> 6;
        #pragma unroll
        for (int r = 0; r < 16; ++r) {
            int kk = r * 4 + kg;
            T[kk][nn] = xb[(size_t)(k0 + kk) * N_ + n0 + nn];
        }
    }
    __syncthreads();
    {
        int kk2 = (t & 31) * 2, ng = t >> 5;
        #pragma unroll
        for (int r = 0; r < 8; ++r) {
            int nn = r * 8 + ng;
            float v0 = T[kk2][nn], v1 = T[kk2 + 1][nn];
            u16 h0 = f2bf_hi(v0), h1 = f2bf_hi(v1);
            u16 l0 = f2bf_hi(v0 - bf2f(h0)), l1 = f2bf_hi(v1 - bf2f(h1));
            size_t o = ((size_t)b * N_ + n0 + nn) * DIM_ + k0 + kk2;
            *(u32*)(hi + o) = (u32)h0 | ((u32)h1 << 16);
            *(u32*)(lo + o) = (u32)l0 | ((u32)l1 << 16);
        }
    }
}

// ---------------------------------------------------------------------------
// Split-bf16 MFMA GEMM (unchanged structure).
// MODE 0: qkv epilogue -> emits qh/ql, kh/kl (hi/lo bf16) and v (bf16) direct.
// MODE 1: proj epilogue -> fp32 out[b, oc, n].
// ---------------------------------------------------------------------------
template<int MODE>
__global__ __launch_bounds__(256) void gemm_split(
    const u16* __restrict__ wh, const u16* __restrict__ wl,
    const u16* __restrict__ xh, const u16* __restrict__ xl,
    const float* __restrict__ bvec, float* __restrict__ outp,
    u16* __restrict__ qh, u16* __restrict__ ql,
    u16* __restrict__ kh, u16* __restrict__ kl, u16* __restrict__ vv,
    int b0, int cb)
{
    __shared__ u16 Wh[128][40], Wl[128][40], Xh[128][40], Xl[128][40];

    const int tid  = threadIdx.x;
    const int lane = tid & 63;
    const int wv   = tid >> 6;
    const int wr   = wv >> 1;
    const int wc   = wv & 1;
    const int bx = blockIdx.x, by = blockIdx.y;
    const int bl = bx >> 1, half = bx & 1;
    const int b  = b0 + bl;

    const size_t wrow0 = (size_t)by * 128;
    const size_t xrow0 = (MODE == 0 ? (size_t)b * N_ : (size_t)bl * N_) + half * 128;

    const int srow = tid >> 2;
    const int skc  = tid & 3;

    f32x4 acc[4][4];
    #pragma unroll
    for (int i = 0; i < 4; ++i)
        #pragma unroll
        for (int j = 0; j < 4; ++j)
            acc[i][j] = (f32x4){0.f, 0.f, 0.f, 0.f};

    const int lrow = lane & 15;
    const int lkc  = (lane >> 4) * 8;

    for (int k0 = 0; k0 < DIM_; k0 += 32) {
        #pragma unroll
        for (int s = 0; s < 2; ++s) {
            int row = srow + s * 64;
            int ko  = k0 + skc * 8;
            size_t wsrc = (wrow0 + row) * DIM_ + ko;
            size_t xsrc = (xrow0 + row) * DIM_ + ko;
            uint4 a0 = *(const uint4*)(wh + wsrc);
            uint4 a1 = *(const uint4*)(wl + wsrc);
            uint4 a2 = *(const uint4*)(xh + xsrc);
            uint4 a3 = *(const uint4*)(xl + xsrc);
            *(uint4*)&Wh[row][skc * 8] = a0;
            *(uint4*)&Wl[row][skc * 8] = a1;
            *(uint4*)&Xh[row][skc * 8] = a2;
            *(uint4*)&Xl[row][skc * 8] = a3;
        }
        __syncthreads();

        short8 ah[4], al[4];
        #pragma unroll
        for (int mt = 0; mt < 4; ++mt) {
            int r = wr * 64 + mt * 16 + lrow;
            ah[mt] = *(const short8*)&Wh[r][lkc];
            al[mt] = *(const short8*)&Wl[r][lkc];
        }
        #pragma unroll
        for (int nt = 0; nt < 4; ++nt) {
            int r = wc * 64 + nt * 16 + lrow;
            short8 bh = *(const short8*)&Xh[r][lkc];
            short8 bo = *(const short8*)&Xl[r][lkc];
            #pragma unroll
            for (int mt = 0; mt < 4; ++mt) {
                acc[mt][nt] = __builtin_amdgcn_mfma_f32_16x16x32_bf16(ah[mt], bh, acc[mt][nt], 0, 0, 0);
                acc[mt][nt] = __builtin_amdgcn_mfma_f32_16x16x32_bf16(ah[mt], bo, acc[mt][nt], 0, 0, 0);
                acc[mt][nt] = __builtin_amdgcn_mfma_f32_16x16x32_bf16(al[mt], bh, acc[mt][nt], 0, 0, 0);
            }
        }
        __syncthreads();
    }

    // C/D layout: col = lane&15 (n), row = (lane>>4)*4 + reg (oc)
    const int ocb = by * 128 + wr * 64 + (lane >> 4) * 4;
    const int nb  = half * 128 + wc * 64 + (lane & 15);

    if (MODE == 0) {
        #pragma unroll
        for (int mt = 0; mt < 4; ++mt) {
            int oc = ocb + mt * 16;
            float4 bv = *(const float4*)(bvec + oc);
            int which = oc / DIM_;           // uniform per block (by-decided)
            int r = oc - which * DIM_;
            int hh = r >> 6, d = r & 63;
            size_t rowbase = ((size_t)bl * NH_ + hh) * (N_ * HD_) + d;
            #pragma unroll
            for (int nt = 0; nt < 4; ++nt) {
                int n = nb + nt * 16;
                size_t idx = rowbase + (size_t)n * HD_;
                float v0 = acc[mt][nt][0] + bv.x;
                float v1 = acc[mt][nt][1] + bv.y;
                float v2 = acc[mt][nt][2] + bv.z;
                float v3 = acc[mt][nt][3] + bv.w;
                union { u16 s[4]; uint2 u; } H;
                H.s[0] = f2bf_hi(v0); H.s[1] = f2bf_hi(v1);
                H.s[2] = f2bf_hi(v2); H.s[3] = f2bf_hi(v3);
                if (which == 2) {
                    *(uint2*)(vv + idx) = H.u;
                } else {
                    union { u16 s[4]; uint2 u; } L;
                    L.s[0] = f2bf_hi(v0 - bf2f(H.s[0]));
                    L.s[1] = f2bf_hi(v1 - bf2f(H.s[1]));
                    L.s[2] = f2bf_hi(v2 - bf2f(H.s[2]));
                    L.s[3] = f2bf_hi(v3 - bf2f(H.s[3]));
                    u16* ph = (which == 0) ? qh : kh;
                    u16* pl = (which == 0) ? ql : kl;
                    *(uint2*)(ph + idx) = H.u;
                    *(uint2*)(pl + idx) = L.u;
                }
            }
        }
    } else {
        #pragma unroll
        for (int mt = 0; mt < 4; ++mt) {
            int oc = ocb + mt * 16;
            float4 bv = *(const float4*)(bvec + oc);
            float* obase = outp + (size_t)b * DIM_ * N_ + (size_t)oc * N_;
            #pragma unroll
            for (int nt = 0; nt < 4; ++nt) {
                int n = nb + nt * 16;
                obase[0 * N_ + n] = acc[mt][nt][0] + bv.x;
                obase[1 * N_ + n] = acc[mt][nt][1] + bv.y;
                obase[2 * N_ + n] = acc[mt][nt][2] + bv.z;
                obase[3 * N_ + n] = acc[mt][nt][3] + bv.w;
            }
        }
    }
}

// ---------------------------------------------------------------------------
// MFMA attention. One block per (bl, h); 4 waves x 64 q-rows.
// S^T = mfma(K, Q) so C-layout rows = kk (4 consecutive per reg -> float4
// bias/fpri loads; softmax over kk = per-lane reduce + shfl 16/32).
// Q,K hi/lo split (3-term); P, V single bf16. P via per-wave LDS round-trip.
// LDS (dynamic 128KB): Kh 32K | Kl 32K | Vt 32K | P 4x8K, all XOR-swizzled.
// ---------------------------------------------------------------------------
__global__ __launch_bounds__(256) void attn_mfma(
    const u16* __restrict__ qh, const u16* __restrict__ ql,
    const u16* __restrict__ kh, const u16* __restrict__ kl,
    const u16* __restrict__ vv,
    const float* __restrict__ bias, const float* __restrict__ fpri,
    u16* __restrict__ aoh, u16* __restrict__ aol,
    int b0, int cb)
{
    extern __shared__ u16 lds[];
    u16* KhL = lds;            // [256][64] u16, idx = r*64 + (kc ^ ((r&7)<<3))
    u16* KlL = lds + 16384;
    u16* VtL = lds + 32768;    // [64][256] u16, idx = d*256 + (kk ^ ((d&7)<<3))
    const int tid  = threadIdx.x;
    const int lane = tid & 63;
    const int wv   = tid >> 6;
    u16* PL = lds + 49152 + wv * 4096;  // [16][256] u16 per wave

    const int bh = blockIdx.x;
    const int bl = bh / NH_, h = bh % NH_;
    const int b  = b0 + bl;
    const size_t base = ((size_t)bl * NH_ + h) * (size_t)(N_ * HD_);

    // stage K hi/lo (swizzled); coalesced 1KB per wave-instr
    #pragma unroll
    for (int s = 0; s < 8; ++s) {
        int chunk = tid + s * 256;            // 0..2047
        int r = chunk >> 3, kc = (chunk & 7) * 8;
        int di = r * 64 + (kc ^ ((r & 7) << 3));
        *(short8*)&KhL[di] = *(const short8*)(kh + base + (size_t)r * 64 + kc);
        *(short8*)&KlL[di] = *(const short8*)(kl + base + (size_t)r * 64 + kc);
    }
    // stage V transposed: lane gathers a d-column chunk (coalesced per instr)
    #pragma unroll
    for (int s = 0; s < 8; ++s) {
        int chunk = tid + s * 256;
        int d = chunk & 63, kkc = (chunk >> 6) * 8;
        union { u16 s[8]; short8 v; } t;
        #pragma unroll
        for (int j = 0; j < 8; ++j)
            t.s[j] = vv[base + (size_t)(kkc + j) * 64 + d];
        *(short8*)&VtL[d * 256 + (kkc ^ ((d & 7) << 3))] = t.v;
    }
    __syncthreads();

    const int l15 = lane & 15;
    const int lg  = lane >> 4;
    const int q0w = wv * 64;

    for (int qt = 0; qt < 4; ++qt) {
        const int qg = q0w + qt * 16 + l15;          // this lane's q column
        const size_t qrow = base + (size_t)qg * 64;
        short8 bqh[2], bql[2];
        #pragma unroll
        for (int c = 0; c < 2; ++c) {
            bqh[c] = *(const short8*)(qh + qrow + lg * 8 + c * 32);
            bql[c] = *(const short8*)(ql + qrow + lg * 8 + c * 32);
        }

        f32x4 sacc[16];
        const float* brow = bias + ((size_t)h * N_ + qg) * N_;
        const float* frow = fpri + ((size_t)b * N_ + qg) * N_;
        #pragma unroll
        for (int kt = 0; kt < 16; ++kt) {
            f32x4 sa = (f32x4){0.f, 0.f, 0.f, 0.f};
            int kr = kt * 16 + l15;
            #pragma unroll
            for (int c = 0; c < 2; ++c) {
                int kc = lg * 8 + c * 32;
                int di = kr * 64 + (kc ^ ((kr & 7) << 3));
                short8 ah = *(const short8*)&KhL[di];
                short8 al = *(const short8*)&KlL[di];
                sa = __builtin_amdgcn_mfma_f32_16x16x32_bf16(ah, bqh[c], sa, 0, 0, 0);
                sa = __builtin_amdgcn_mfma_f32_16x16x32_bf16(ah, bql[c], sa, 0, 0, 0);
                sa = __builtin_amdgcn_mfma_f32_16x16x32_bf16(al, bqh[c], sa, 0, 0, 0);
            }
            float4 bs = *(const float4*)(brow + kt * 16 + lg * 4);
            float4 fs = *(const float4*)(frow + kt * 16 + lg * 4);
            sacc[kt][0] = (sa[0] * 0.125f + bs.x) * fs.x;
            sacc[kt][1] = (sa[1] * 0.125f + bs.y) * fs.y;
            sacc[kt][2] = (sa[2] * 0.125f + bs.z) * fs.z;
            sacc[kt][3] = (sa[3] * 0.125f + bs.w) * fs.w;
        }

        // softmax over kk: per-lane 64 values + cross-group shfl
        float m = -1e30f;
        #pragma unroll
        for (int kt = 0; kt < 16; ++kt) {
            m = fmaxf(m, fmaxf(fmaxf(sacc[kt][0], sacc[kt][1]),
                               fmaxf(sacc[kt][2], sacc[kt][3])));
        }
        m = fmaxf(m, __shfl_xor(m, 16));
        m = fmaxf(m, __shfl_xor(m, 32));
        float lsum = 0.f;
        #pragma unroll
        for (int kt = 0; kt < 16; ++kt) {
            #pragma unroll
            for (int j = 0; j < 4; ++j) {
                float p = __expf(sacc[kt][j] - m);
                sacc[kt][j] = p;
                lsum += p;
            }
        }
        lsum += __shfl_xor(lsum, 16);
        lsum += __shfl_xor(lsum, 32);

        // P -> bf16 -> per-wave LDS (C-frag write, B-frag read)
        #pragma unroll
        for (int kt = 0; kt < 16; ++kt) {
            int kk = kt * 16 + lg * 4;
            union { u16 s[4]; uint2 u; } pw;
            pw.s[0] = f2bf_hi(sacc[kt][0]);
            pw.s[1] = f2bf_hi(sacc[kt][1]);
            pw.s[2] = f2bf_hi(sacc[kt][2]);
            pw.s[3] = f2bf_hi(sacc[kt][3]);
            *(uint2*)&PL[l15 * 256 + (kk ^ ((l15 & 7) << 3))] = pw.u;
        }

        // O^T = Vt . P : rows d, cols q
        f32x4 oacc[4];
        #pragma unroll
        for (int dt = 0; dt < 4; ++dt) oacc[dt] = (f32x4){0.f, 0.f, 0.f, 0.f};
        #pragma unroll
        for (int c2 = 0; c2 < 8; ++c2) {
            int kc2 = lg * 8 + c2 * 32;
            short8 bp = *(const short8*)&PL[l15 * 256 + (kc2 ^ ((l15 & 7) << 3))];
            #pragma unroll
            for (int dt = 0; dt < 4; ++dt) {
                int dr = dt * 16 + l15;
                short8 av = *(const short8*)&VtL[dr * 256 + (kc2 ^ ((dr & 7) << 3))];
                oacc[dt] = __builtin_amdgcn_mfma_f32_16x16x32_bf16(av, bp, oacc[dt], 0, 0, 0);
            }
        }

        float inv = 1.f / lsum;
        size_t orow = ((size_t)bl * N_ + qg) * DIM_ + h * HD_;
        #pragma unroll
        for (int dt = 0; dt < 4; ++dt) {
            int d0 = dt * 16 + lg * 4;
            union { u16 s[4]; uint2 u; } H, L;
            #pragma unroll
            for (int j = 0; j < 4; ++j) {
                float vf = oacc[dt][j] * inv;
                u16 hh = f2bf_hi(vf);
                H.s[j] = hh;
                L.s[j] = f2bf_hi(vf - bf2f(hh));
            }
            *(uint2*)(aoh + orow + d0) = H.u;
            *(uint2*)(aol + orow + d0) = L.u;
        }
    }
}

// ---------------------------------------------------------------------------
extern "C" void kernel_launch(void* const* d_in, const int* in_sizes, int n_in,
                              void* d_out, int out_size, void* d_ws, size_t ws_size,
                              hipStream_t stream)
{
    const float* x           = (const float*)d_in[0];
    const float* face_priors = (const float*)d_in[1];
    const float* qkv_w       = (const float*)d_in[2];
    const float* qkv_b       = (const float*)d_in[3];
    const float* rel_table   = (const float*)d_in[4];
    const float* face_prior  = (const float*)d_in[5];
    const float* proj_w      = (const float*)d_in[6];
    const float* proj_b      = (const float*)d_in[7];
    float* out = (float*)d_out;

    // persistent: bias 3.0MB + x splits 96MB + w splits 9MB = 113246208 B
    // per-chunk: qh/ql/kh/kl/vv + aoh/aol = 7 * cb * 393216 B = cb * 2752512 B
    float* ws   = (float*)d_ws;
    float* bias = ws;
    u16* xah = (u16*)(bias + 786432);
    u16* xal = xah + (size_t)B_ * N_ * DIM_;
    u16* qwh = xal + (size_t)B_ * N_ * DIM_;
    u16* qwl = qwh + (size_t)3 * DIM_ * DIM_;
    u16* pwh = qwl + (size_t)3 * DIM_ * DIM_;
    u16* pwl = pwh + (size_t)DIM_ * DIM_;
    u16* cbase = pwl + (size_t)DIM_ * DIM_;

    int CB = 1;
    const int cands[] = {128, 64, 32, 16, 8, 4, 2, 1};
    for (int ci = 0; ci < 8; ++ci) {
        if (113246208ull + (size_t)cands[ci] * 2752512ull <= ws_size) { CB = cands[ci]; break; }
    }
    const size_t SL = (size_t)CB * NH_ * N_ * HD_;   // u16 per q/k/v slab
    u16* qhb = cbase;
    u16* qlb = qhb + SL;
    u16* khb = qlb + SL;
    u16* klb = khb + SL;
    u16* vvb = klb + SL;
    u16* aoh = vvb + SL;
    u16* aol = aoh + (size_t)CB * N_ * DIM_;

    hipFuncSetAttribute((const void*)attn_mfma,
                        hipFuncAttributeMaxDynamicSharedMemorySize, 131072);

    bias_kernel<<<(NH_ * N_ * N_) / 256, 256, 0, stream>>>(face_prior, rel_table, bias);
    split_w_kernel<<<(3 * DIM_ * DIM_ / 8 + 255) / 256, 256, 0, stream>>>(qkv_w, qwh, qwl, 3 * DIM_ * DIM_ / 8);
    split_w_kernel<<<(DIM_ * DIM_ / 8 + 255) / 256, 256, 0, stream>>>(proj_w, pwh, pwl, DIM_ * DIM_ / 8);
    split_transpose_x<<<dim3(12, 4, B_), 256, 0, stream>>>(x, xah, xal);

    for (int b0 = 0; b0 < B_; b0 += CB) {
        gemm_split<0><<<dim3(CB * 2, 18), 256, 0, stream>>>(
            qwh, qwl, xah, xal, qkv_b, nullptr, qhb, qlb, khb, klb, vvb, b0, CB);

        attn_mfma<<<CB * NH_, 256, 131072, stream>>>(
            qhb, qlb, khb, klb, vvb, bias, face_priors, aoh, aol, b0, CB);

        gemm_split<1><<<dim3(CB * 2, 6), 256, 0, stream>>>(
            pwh, pwl, aoh, aol, proj_b, out,
            nullptr, nullptr, nullptr, nullptr, nullptr, b0, CB);
    }
}